// Round 1
// baseline (2523.552 us; speedup 1.0000x reference)
//
#include <hip/hip_runtime.h>
#include <stdint.h>
#include <stddef.h>

// B=256, C_IN=2048, L=150 (padded to 160), C=256, H1=8192, OUT=2048
// Pipeline: k_pv -> k_qk -> k_attn -> k_init -> k_fc1 -> k_fc2
// All GEMMs: bf16 MFMA 16x16x32, fp32 accum. LDS tiles row-stride 40 (=BK32+8 pad).

typedef __bf16 bf16x8 __attribute__((ext_vector_type(8)));
typedef float  f32x4  __attribute__((ext_vector_type(4)));

#define MFMA(a, b, c) __builtin_amdgcn_mfma_f32_16x16x32_bf16(a, b, c, 0, 0, 0)

// Load 16 contiguous fp32, convert to bf16, store 16 to LDS (dst 16B-aligned).
__device__ inline void stage16(const float* __restrict__ src, __bf16* dst) {
    const float4* s4 = (const float4*)src;
    float4 a = s4[0], b = s4[1], c = s4[2], d = s4[3];
    union { __bf16 t[16]; bf16x8 v[2]; } u;
    u.t[0]=(__bf16)a.x; u.t[1]=(__bf16)a.y; u.t[2]=(__bf16)a.z; u.t[3]=(__bf16)a.w;
    u.t[4]=(__bf16)b.x; u.t[5]=(__bf16)b.y; u.t[6]=(__bf16)b.z; u.t[7]=(__bf16)b.w;
    u.t[8]=(__bf16)c.x; u.t[9]=(__bf16)c.y; u.t[10]=(__bf16)c.z; u.t[11]=(__bf16)c.w;
    u.t[12]=(__bf16)d.x; u.t[13]=(__bf16)d.y; u.t[14]=(__bf16)d.z; u.t[15]=(__bf16)d.w;
    *(bf16x8*)dst = u.v[0];
    *(bf16x8*)(dst + 8) = u.v[1];
}

// ---------------------------------------------------------------------------
// K1: pv[b,o,l] = sum_c Wv[o,c]*x[b,c,l] + bv[o]   (NN GEMM, x transposed in LDS)
// writes pv [b,256,160] bf16 (l>=150 -> bias) and pvT [b,160,256] bf16 (pad rows 0)
// grid 512 = 2 m-tiles x 256 batches, XCD-swizzled so both m-tiles of a batch
// share an XCD's L2 copy of x_b (1.23MB).
// ---------------------------------------------------------------------------
__global__ __launch_bounds__(256, 2) void k_pv(
        const float* __restrict__ x, const float* __restrict__ Wv,
        const float* __restrict__ bv, __bf16* __restrict__ pv,
        __bf16* __restrict__ pvT) {
    __shared__ __align__(16) __bf16 As[128*40];    // Wv tile [o_loc][k]
    __shared__ __align__(16) __bf16 BTs[160*40];   // x tile transposed [l][k]
    __shared__ __align__(16) __bf16 Ts[128*162];   // transpose buf for pvT

    int p = blockIdx.x;
    int xcd = p & 7, slot = p >> 3;
    int mt = slot & 1;
    int b  = ((slot >> 1) << 3) + xcd;
    const float* xb = x + (size_t)b * (2048*150);

    int tid = threadIdx.x;
    int w = tid >> 6, lane = tid & 63, q = lane >> 4, l15 = lane & 15;
    int wm = w & 1, wn = w >> 1;   // wave covers rows wm*64(4 frags) x cols wn*80(5 frags)

    f32x4 acc[4][5];
#pragma unroll
    for (int i = 0; i < 4; ++i)
#pragma unroll
        for (int j = 0; j < 5; ++j) acc[i][j] = (f32x4)0.0f;

    int arow = tid >> 1, ahalf = tid & 1;
    for (int k0 = 0; k0 < 2048; k0 += 32) {
        __syncthreads();
        stage16(Wv + (size_t)(mt*128 + arow)*2048 + k0 + ahalf*16,
                &As[arow*40 + ahalf*16]);
        // x rows -> transposed LDS: wave w stages k-rows w,w+4,...
#pragma unroll
        for (int rr = 0; rr < 8; ++rr) {
            int r = w + 4*rr;
            const float* srcrow = xb + (size_t)(k0 + r)*150;
#pragma unroll
            for (int j3 = 0; j3 < 3; ++j3) {
                int l = lane + 64*j3;
                if (l < 150)      BTs[l*40 + r] = (__bf16)srcrow[l];
                else if (l < 160) BTs[l*40 + r] = (__bf16)0.0f;
            }
        }
        __syncthreads();
        bf16x8 af[4], bfv[5];
#pragma unroll
        for (int i = 0; i < 4; ++i)
            af[i] = *(const bf16x8*)&As[(wm*64 + i*16 + l15)*40 + q*8];
#pragma unroll
        for (int j = 0; j < 5; ++j)
            bfv[j] = *(const bf16x8*)&BTs[(wn*80 + j*16 + l15)*40 + q*8];
#pragma unroll
        for (int i = 0; i < 4; ++i)
#pragma unroll
            for (int j = 0; j < 5; ++j) acc[i][j] = MFMA(af[i], bfv[j], acc[i][j]);
    }

    float bvv[4][4];
#pragma unroll
    for (int i = 0; i < 4; ++i)
#pragma unroll
        for (int r = 0; r < 4; ++r) bvv[i][r] = bv[mt*128 + wm*64 + i*16 + q*4 + r];

#pragma unroll
    for (int i = 0; i < 4; ++i)
#pragma unroll
        for (int j = 0; j < 5; ++j)
#pragma unroll
            for (int r = 0; r < 4; ++r) {
                int ol = wm*64 + i*16 + q*4 + r;
                int o  = mt*128 + ol;
                int l  = wn*80 + j*16 + l15;
                __bf16 hv = (__bf16)(acc[i][j][r] + bvv[i][r]);
                pv[((size_t)b*256 + o)*160 + l] = hv;
                Ts[ol*162 + l] = hv;
            }
    __syncthreads();
    // pvT[b][l][mt*128 .. +128) coalesced 16B stores
#pragma unroll
    for (int j = 0; j < 10; ++j) {
        int idx = tid + 256*j;              // < 2560
        int l = idx >> 4, sub = idx & 15;
        union { __bf16 t[8]; bf16x8 v; } u;
#pragma unroll
        for (int e = 0; e < 8; ++e) u.t[e] = Ts[(sub*8 + e)*162 + l];
        *(bf16x8*)&pvT[((size_t)b*160 + l)*256 + mt*128 + sub*8] = u.v;
    }
}

// ---------------------------------------------------------------------------
// K2: qkT[b,l,n] = sum_c pvT[b,l,c]*Wqk[n,c] + bqk[n]   (NT GEMM)
// n<256 -> Wq/bq (q), n>=256 -> Wk/bk (k). tile 160x128, grid 1024.
// ---------------------------------------------------------------------------
__global__ __launch_bounds__(256, 2) void k_qk(
        const __bf16* __restrict__ pvT,
        const float* __restrict__ Wq, const float* __restrict__ bq,
        const float* __restrict__ Wk, const float* __restrict__ bk,
        __bf16* __restrict__ qkT) {
    __shared__ __align__(16) __bf16 As[160*40];
    __shared__ __align__(16) __bf16 Bs[128*40];

    int p = blockIdx.x;
    int xcd = p & 7, slot = p >> 3;
    int nt = slot & 3;
    int b  = ((slot >> 2) << 3) + xcd;

    const float* W  = (nt < 2) ? Wq : Wk;
    const float* bb = (nt < 2) ? bq : bk;
    int nbase = nt*128 - ((nt < 2) ? 0 : 256);   // row base within W

    int tid = threadIdx.x;
    int w = tid >> 6, lane = tid & 63, q = lane >> 4, l15 = lane & 15;
    int wm = w & 1, wn = w >> 1;   // rows wm*80 (5 frags) x cols wn*64 (4 frags)

    const __bf16* pvTb = pvT + (size_t)b*160*256;

    f32x4 acc[5][4];
#pragma unroll
    for (int i = 0; i < 5; ++i)
#pragma unroll
        for (int j = 0; j < 4; ++j) acc[i][j] = (f32x4)0.0f;

    int brow = tid >> 1, bhalf = tid & 1;
    for (int k0 = 0; k0 < 256; k0 += 32) {
        __syncthreads();
#pragma unroll
        for (int j3 = 0; j3 < 3; ++j3) {
            int idx = tid + 256*j3;
            if (idx < 640) {
                int row = idx >> 2, sub = idx & 3;
                *(bf16x8*)&As[row*40 + sub*8] =
                    *(const bf16x8*)&pvTb[(size_t)row*256 + k0 + sub*8];
            }
        }
        stage16(W + (size_t)(nbase + brow)*256 + k0 + bhalf*16,
                &Bs[brow*40 + bhalf*16]);
        __syncthreads();
        bf16x8 af[5], bfv[4];
#pragma unroll
        for (int i = 0; i < 5; ++i)
            af[i] = *(const bf16x8*)&As[(wm*80 + i*16 + l15)*40 + q*8];
#pragma unroll
        for (int j = 0; j < 4; ++j)
            bfv[j] = *(const bf16x8*)&Bs[(wn*64 + j*16 + l15)*40 + q*8];
#pragma unroll
        for (int i = 0; i < 5; ++i)
#pragma unroll
            for (int j = 0; j < 4; ++j) acc[i][j] = MFMA(af[i], bfv[j], acc[i][j]);
    }

    float biasj[4];
#pragma unroll
    for (int j = 0; j < 4; ++j) biasj[j] = bb[nbase + wn*64 + j*16 + l15];

#pragma unroll
    for (int i = 0; i < 5; ++i)
#pragma unroll
        for (int j = 0; j < 4; ++j)
#pragma unroll
            for (int r = 0; r < 4; ++r) {
                int l = wm*80 + i*16 + q*4 + r;
                int n = nt*128 + wn*64 + j*16 + l15;
                qkT[((size_t)b*160 + l)*512 + n] = (__bf16)(acc[i][j][r] + biasj[j]);
            }
}

// ---------------------------------------------------------------------------
// K3: per-batch fused attention.
//   energy = qT*kT^T (160x160, K=256) -> masked softmax rows (cols<150)
//   out[c,l] = sum_m pv[c,m]*att[l,m];  flat = bf16(gamma*out + pv)
// LDS: [Ats 12800 | att(=Bts) 51200] = 64000 B; red buffers alias Ats.
// ---------------------------------------------------------------------------
__global__ __launch_bounds__(256, 1) void k_attn(
        const __bf16* __restrict__ qkT, const __bf16* __restrict__ pv,
        const float* __restrict__ gamma, __bf16* __restrict__ flat) {
    __shared__ __align__(16) char lds3[64000];
    __bf16* Ats  = (__bf16*)lds3;            // 160*40 (A) / 128*40 (phase B)
    __bf16* Bts  = (__bf16*)(lds3 + 12800);  // 160*40 (kT tile, phase A)
    __bf16* att  = (__bf16*)(lds3 + 12800);  // 160*160 bf16 (after softmax)
    float*  redm = (float*)lds3;             // 160*2
    float*  reds = (float*)(lds3 + 1280);    // 160*2

    int b = blockIdx.x;
    int tid = threadIdx.x;
    int w = tid >> 6, lane = tid & 63, q = lane >> 4, l15 = lane & 15;
    int wm = w & 1, wn = w >> 1;

    const __bf16* qkTb = qkT + (size_t)b*160*512;
    const __bf16* pvb  = pv  + (size_t)b*256*160;

    // ---- phase A: energy (rows wm*80, 5 frags) x (cols wn*80, 5 frags) ----
    f32x4 e[5][5];
#pragma unroll
    for (int i = 0; i < 5; ++i)
#pragma unroll
        for (int j = 0; j < 5; ++j) e[i][j] = (f32x4)0.0f;

    for (int k0 = 0; k0 < 256; k0 += 32) {
        __syncthreads();
#pragma unroll
        for (int t2 = 0; t2 < 2; ++t2) {
            __bf16* dst = t2 ? Bts : Ats;
            int coff = k0 + t2*256;
#pragma unroll
            for (int j3 = 0; j3 < 3; ++j3) {
                int idx = tid + 256*j3;
                if (idx < 640) {
                    int row = idx >> 2, sub = idx & 3;
                    *(bf16x8*)&dst[row*40 + sub*8] =
                        *(const bf16x8*)&qkTb[(size_t)row*512 + coff + sub*8];
                }
            }
        }
        __syncthreads();
        bf16x8 af[5], bfv[5];
#pragma unroll
        for (int i = 0; i < 5; ++i)
            af[i] = *(const bf16x8*)&Ats[(wm*80 + i*16 + l15)*40 + q*8];
#pragma unroll
        for (int j = 0; j < 5; ++j)
            bfv[j] = *(const bf16x8*)&Bts[(wn*80 + j*16 + l15)*40 + q*8];
#pragma unroll
        for (int i = 0; i < 5; ++i)
#pragma unroll
            for (int j = 0; j < 5; ++j) e[i][j] = MFMA(af[i], bfv[j], e[i][j]);
    }

    // ---- masked softmax over cols (j dim), rows = l ----
    float rmax[5][4];
#pragma unroll
    for (int i = 0; i < 5; ++i)
#pragma unroll
        for (int r = 0; r < 4; ++r) {
            float m = -3.0e38f;
#pragma unroll
            for (int j = 0; j < 5; ++j) {
                int col = wn*80 + j*16 + l15;
                if (col < 150) m = fmaxf(m, e[i][j][r]);
            }
            rmax[i][r] = m;
        }
#pragma unroll
    for (int d = 1; d <= 8; d <<= 1)
#pragma unroll
        for (int i = 0; i < 5; ++i)
#pragma unroll
            for (int r = 0; r < 4; ++r)
                rmax[i][r] = fmaxf(rmax[i][r], __shfl_xor(rmax[i][r], d));
    __syncthreads();                      // last MFMA read of Ats done
    if (l15 == 0) {
#pragma unroll
        for (int i = 0; i < 5; ++i)
#pragma unroll
            for (int r = 0; r < 4; ++r)
                redm[(wm*80 + i*16 + q*4 + r)*2 + wn] = rmax[i][r];
    }
    __syncthreads();
    float mfull[5][4], rsum[5][4];
#pragma unroll
    for (int i = 0; i < 5; ++i)
#pragma unroll
        for (int r = 0; r < 4; ++r) {
            int row = wm*80 + i*16 + q*4 + r;
            mfull[i][r] = fmaxf(redm[row*2], redm[row*2 + 1]);
            rsum[i][r] = 0.0f;
        }
#pragma unroll
    for (int i = 0; i < 5; ++i)
#pragma unroll
        for (int j = 0; j < 5; ++j)
#pragma unroll
            for (int r = 0; r < 4; ++r) {
                int col = wn*80 + j*16 + l15;
                float v = 0.0f;
                if (col < 150) {
                    v = __expf(e[i][j][r] - mfull[i][r]);
                    rsum[i][r] += v;
                }
                e[i][j][r] = v;
            }
#pragma unroll
    for (int d = 1; d <= 8; d <<= 1)
#pragma unroll
        for (int i = 0; i < 5; ++i)
#pragma unroll
            for (int r = 0; r < 4; ++r)
                rsum[i][r] += __shfl_xor(rsum[i][r], d);
    if (l15 == 0) {
#pragma unroll
        for (int i = 0; i < 5; ++i)
#pragma unroll
            for (int r = 0; r < 4; ++r)
                reds[(wm*80 + i*16 + q*4 + r)*2 + wn] = rsum[i][r];
    }
    __syncthreads();
#pragma unroll
    for (int i = 0; i < 5; ++i)
#pragma unroll
        for (int r = 0; r < 4; ++r) {
            int row = wm*80 + i*16 + q*4 + r;
            float inv = 1.0f / (reds[row*2] + reds[row*2 + 1]);
#pragma unroll
            for (int j = 0; j < 5; ++j) {
                int col = wn*80 + j*16 + l15;
                att[row*160 + col] = (__bf16)(e[i][j][r] * inv);
            }
        }
    __syncthreads();

    // ---- phase B: out[c,l] = sum_m pv[c,m]*att[l,m], 2 passes of 128 c-rows ----
    float g = gamma[0];
    for (int pass = 0; pass < 2; ++pass) {
        f32x4 o4[4][5];
#pragma unroll
        for (int i = 0; i < 4; ++i)
#pragma unroll
            for (int j = 0; j < 5; ++j) o4[i][j] = (f32x4)0.0f;

        for (int k0 = 0; k0 < 160; k0 += 32) {
            __syncthreads();
#pragma unroll
            for (int j2 = 0; j2 < 2; ++j2) {
                int idx = tid + 256*j2;         // < 512
                int row = idx >> 2, sub = idx & 3;
                *(bf16x8*)&Ats[row*40 + sub*8] =
                    *(const bf16x8*)&pvb[(size_t)(pass*128 + row)*160 + k0 + sub*8];
            }
            __syncthreads();
            bf16x8 af[4], bfv[5];
#pragma unroll
            for (int i = 0; i < 4; ++i)
                af[i] = *(const bf16x8*)&Ats[(wm*64 + i*16 + l15)*40 + q*8];
#pragma unroll
            for (int j = 0; j < 5; ++j)
                bfv[j] = *(const bf16x8*)&att[(wn*80 + j*16 + l15)*160 + k0 + q*8];
#pragma unroll
            for (int i = 0; i < 4; ++i)
#pragma unroll
                for (int j = 0; j < 5; ++j) o4[i][j] = MFMA(af[i], bfv[j], o4[i][j]);
        }
#pragma unroll
        for (int i = 0; i < 4; ++i)
#pragma unroll
            for (int j = 0; j < 5; ++j)
#pragma unroll
                for (int r = 0; r < 4; ++r) {
                    int c = pass*128 + wm*64 + i*16 + q*4 + r;
                    int l = wn*80 + j*16 + l15;
                    if (l < 150) {
                        float pvv = (float)pvb[(size_t)c*160 + l];
                        flat[(size_t)b*38400 + c*150 + l] =
                            (__bf16)(g*o4[i][j][r] + pvv);
                    }
                }
    }
}

// ---------------------------------------------------------------------------
// k_init: h = b1 broadcast (256x8192), d_out = b2 broadcast (256x2048)
// ---------------------------------------------------------------------------
__global__ __launch_bounds__(256) void k_init(
        float* __restrict__ h, float* __restrict__ out,
        const float* __restrict__ b1, const float* __restrict__ b2) {
    int i = blockIdx.x*256 + threadIdx.x;      // float4 index, grid = 2560
    if (i < 524288) {
        *(float4*)&h[(size_t)i*4] = *(const float4*)&b1[(i*4) & 8191];
    } else {
        int j = i - 524288;                    // < 131072
        *(float4*)&out[(size_t)j*4] = *(const float4*)&b2[(j*4) & 2047];
    }
}

// ---------------------------------------------------------------------------
// K4: fc1: h[m,n] += sum_k flat[m,k]*W1[n,k]  (NT, split-K=4, atomics)
// grid 512 = 2m x 64n x 4s, XCD-swizzled so the (m=0,m=1) pair sharing a W1
// slice lands adjacent on one XCD (L2 reuse -> W1 HBM read ~1x).
// ---------------------------------------------------------------------------
__global__ __launch_bounds__(256, 2) void k_fc1(
        const __bf16* __restrict__ flat, const float* __restrict__ W1,
        float* __restrict__ h) {
    __shared__ __align__(16) __bf16 As[128*40];
    __shared__ __align__(16) __bf16 Bs[128*40];

    int p = blockIdx.x;
    int xcd = p & 7, slot = p >> 3;
    int mt = slot & 1;
    int id2 = ((slot >> 1) << 3) + xcd;   // [0,256)
    int nt = id2 >> 2, s = id2 & 3;
    int kbase = s * 9600;

    int tid = threadIdx.x;
    int w = tid >> 6, lane = tid & 63, q = lane >> 4, l15 = lane & 15;
    int wm = w & 1, wn = w >> 1;

    f32x4 acc[4][4];
#pragma unroll
    for (int i = 0; i < 4; ++i)
#pragma unroll
        for (int j = 0; j < 4; ++j) acc[i][j] = (f32x4)0.0f;

    int brow = tid >> 1, bhalf = tid & 1;
    for (int k0 = kbase; k0 < kbase + 9600; k0 += 32) {
        __syncthreads();
#pragma unroll
        for (int j2 = 0; j2 < 2; ++j2) {
            int idx = tid + 256*j2;            // < 512
            int row = idx >> 2, sub = idx & 3;
            *(bf16x8*)&As[row*40 + sub*8] =
                *(const bf16x8*)&flat[(size_t)(mt*128 + row)*38400 + k0 + sub*8];
        }
        stage16(W1 + (size_t)(nt*128 + brow)*38400 + k0 + bhalf*16,
                &Bs[brow*40 + bhalf*16]);
        __syncthreads();
        bf16x8 af[4], bfv[4];
#pragma unroll
        for (int i = 0; i < 4; ++i)
            af[i] = *(const bf16x8*)&As[(wm*64 + i*16 + l15)*40 + q*8];
#pragma unroll
        for (int j = 0; j < 4; ++j)
            bfv[j] = *(const bf16x8*)&Bs[(wn*64 + j*16 + l15)*40 + q*8];
#pragma unroll
        for (int i = 0; i < 4; ++i)
#pragma unroll
            for (int j = 0; j < 4; ++j) acc[i][j] = MFMA(af[i], bfv[j], acc[i][j]);
    }
#pragma unroll
    for (int i = 0; i < 4; ++i)
#pragma unroll
        for (int j = 0; j < 4; ++j)
#pragma unroll
            for (int r = 0; r < 4; ++r) {
                int m = mt*128 + wm*64 + i*16 + q*4 + r;
                int n = nt*128 + wn*64 + j*16 + l15;
                atomicAdd(&h[(size_t)m*8192 + n], acc[i][j][r]);
            }
}

// ---------------------------------------------------------------------------
// K5: fc2: out[m,n] += sum_k h[m,k]*W2[n,k]  (NT, split-K=8, atomics)
// grid 256 = 2m x 16n x 8s, same swizzle idea.
// ---------------------------------------------------------------------------
__global__ __launch_bounds__(256, 2) void k_fc2(
        const float* __restrict__ h, const float* __restrict__ W2,
        float* __restrict__ out) {
    __shared__ __align__(16) __bf16 As[128*40];
    __shared__ __align__(16) __bf16 Bs[128*40];

    int p = blockIdx.x;
    int xcd = p & 7, slot = p >> 3;
    int mt = slot & 1;
    int id2 = ((slot >> 1) << 3) + xcd;   // [0,128)
    int nt = id2 >> 3, s = id2 & 7;
    int kbase = s * 1024;

    int tid = threadIdx.x;
    int w = tid >> 6, lane = tid & 63, q = lane >> 4, l15 = lane & 15;
    int wm = w & 1, wn = w >> 1;

    f32x4 acc[4][4];
#pragma unroll
    for (int i = 0; i < 4; ++i)
#pragma unroll
        for (int j = 0; j < 4; ++j) acc[i][j] = (f32x4)0.0f;

    int row2 = tid >> 1, half2 = tid & 1;
    for (int k0 = kbase; k0 < kbase + 1024; k0 += 32) {
        __syncthreads();
        stage16(h  + (size_t)(mt*128 + row2)*8192 + k0 + half2*16,
                &As[row2*40 + half2*16]);
        stage16(W2 + (size_t)(nt*128 + row2)*8192 + k0 + half2*16,
                &Bs[row2*40 + half2*16]);
        __syncthreads();
        bf16x8 af[4], bfv[4];
#pragma unroll
        for (int i = 0; i < 4; ++i)
            af[i] = *(const bf16x8*)&As[(wm*64 + i*16 + l15)*40 + q*8];
#pragma unroll
        for (int j = 0; j < 4; ++j)
            bfv[j] = *(const bf16x8*)&Bs[(wn*64 + j*16 + l15)*40 + q*8];
#pragma unroll
        for (int i = 0; i < 4; ++i)
#pragma unroll
            for (int j = 0; j < 4; ++j) acc[i][j] = MFMA(af[i], bfv[j], acc[i][j]);
    }
#pragma unroll
    for (int i = 0; i < 4; ++i)
#pragma unroll
        for (int j = 0; j < 4; ++j)
#pragma unroll
            for (int r = 0; r < 4; ++r) {
                int m = mt*128 + wm*64 + i*16 + q*4 + r;
                int n = nt*128 + wn*64 + j*16 + l15;
                atomicAdd(&out[(size_t)m*2048 + n], acc[i][j][r]);
            }
}

// ---------------------------------------------------------------------------
extern "C" void kernel_launch(void* const* d_in, const int* in_sizes, int n_in,
                              void* d_out, int out_size, void* d_ws, size_t ws_size,
                              hipStream_t stream) {
    (void)in_sizes; (void)n_in; (void)out_size; (void)ws_size;
    const float* x     = (const float*)d_in[0];
    const float* Wv    = (const float*)d_in[1];
    const float* bv    = (const float*)d_in[2];
    const float* Wq    = (const float*)d_in[3];
    const float* bq    = (const float*)d_in[4];
    const float* Wk    = (const float*)d_in[5];
    const float* bk    = (const float*)d_in[6];
    const float* gamma = (const float*)d_in[7];
    const float* W1    = (const float*)d_in[8];
    const float* b1    = (const float*)d_in[9];
    const float* W2    = (const float*)d_in[10];
    const float* b2    = (const float*)d_in[11];

    char* ws = (char*)d_ws;
    // ws layout (needs ~103.6 MB):
    __bf16* pv   = (__bf16*)(ws);               // 256*256*160*2 = 20,971,520
    __bf16* pvT  = (__bf16*)(ws + 20971520);    // 256*160*256*2 = 20,971,520
    __bf16* qkT  = (__bf16*)(ws + 41943040);    // 256*160*512*2 = 41,943,040
    __bf16* flat = (__bf16*)(ws + 83886080);    // 256*38400*2   = 19,660,800
    float*  h    = (float*)(ws);                // aliases pv (dead after k_attn)
    float*  out  = (float*)d_out;

    k_pv  <<<dim3(512),  dim3(256), 0, stream>>>(x, Wv, bv, pv, pvT);
    k_qk  <<<dim3(1024), dim3(256), 0, stream>>>(pvT, Wq, bq, Wk, bk, qkT);
    k_attn<<<dim3(256),  dim3(256), 0, stream>>>(qkT, pv, gamma, flat);
    k_init<<<dim3(2560), dim3(256), 0, stream>>>(h, out, b1, b2);   // after k_attn: h aliases pv
    k_fc1 <<<dim3(512),  dim3(256), 0, stream>>>(flat, W1, h);
    k_fc2 <<<dim3(256),  dim3(256), 0, stream>>>(h, W2, out);
}